// Round 7
// baseline (408.992 us; speedup 1.0000x reference)
//
#include <hip/hip_runtime.h>
#include <stdint.h>

#define Bv 2
#define Cv 256
#define Nv 4096
#define NHv 4
#define HDv 64
#define Kv 16

// R13: attn = R12 body + pc prefetch depth-2 (pcA/pcB ping-pong, the R11
// pipeline WITHOUT the launch-bounds cap that caused the 64-VGPR spill).
// mm1b/mm2b (N=256, K=512) move to 32-row tiles: 1024 blocks (4/CU) vs 512.
// Everything else = R12 (best measured: 396.2).

typedef __attribute__((ext_vector_type(8))) short bf16x8;
typedef __attribute__((ext_vector_type(4))) float f32x4;

__device__ __forceinline__ float bf2f(unsigned short u) {
  union { unsigned int i; float f; } x; x.i = ((unsigned int)u) << 16; return x.f;
}
__device__ __forceinline__ unsigned short f2bf(float f) {
  union { float f; unsigned int i; } x; x.f = f;
  unsigned int r = x.i + 0x7FFF + ((x.i >> 16) & 1);   // RNE
  return (unsigned short)(r >> 16);
}
__device__ __forceinline__ unsigned int cvt_pk_bf16(float lo, float hi) {
  unsigned int r;
  asm("v_cvt_pk_bf16_f32 %0, %1, %2" : "=v"(r) : "v"(lo), "v"(hi));
  return r;
}
__device__ __forceinline__ float exp2_raw(float x) {
  float r;
  asm("v_exp_f32 %0, %1" : "=v"(r) : "v"(x));
  return r;
}

// ---------------------------------------------------------------------------
// Prep 1: img [b][c][n] fp32 -> imgT [z][n][c] bf16  (z = img*2 + b, z<6)
// ---------------------------------------------------------------------------
__global__ __launch_bounds__(256) void imgt_k(
    const float* __restrict__ qi, const float* __restrict__ ki,
    const float* __restrict__ vi, unsigned short* __restrict__ dst)
{
  const int z = blockIdx.z;
  const float* src = (z < 2 ? qi : (z < 4 ? ki : vi)) + (long long)(z & 1) * Cv * Nv;
  unsigned short* out = dst + (long long)z * Nv * Cv;
  __shared__ float t[32][33];
  const int x = threadIdx.x, y = threadIdx.y;
  const int n0 = blockIdx.x * 32, c0 = blockIdx.y * 32;
  for (int i = y; i < 32; i += 8)
    t[i][x] = src[(long long)(c0 + i) * Nv + n0 + x];
  __syncthreads();
  for (int i = y; i < 32; i += 8)
    out[(long long)(n0 + i) * Cv + c0 + x] = f2bf(t[x][i]);
}

// ---------------------------------------------------------------------------
// Prep 2: W [k][n] fp32 -> Wt [n][k] bf16 (z<7); z==7 zeros cent/cnts
// ---------------------------------------------------------------------------
struct WP { const float* p[7]; };

__global__ __launch_bounds__(256) void wt_k(WP wp, unsigned short* __restrict__ dst,
                                            float* __restrict__ zp, int zn)
{
  const int z = blockIdx.z;
  if (z == 7) {
    const int idx = (blockIdx.y * 16 + blockIdx.x) * 256 + threadIdx.y * 32 + threadIdx.x;
    if (idx < zn) zp[idx] = 0.f;
    return;
  }
  const int KD[7] = {256, 256, 256, 256, 512, 256, 512};
  const int ND[7] = {256, 256, 256, 512, 256, 512, 256};
  const long long OFF[7] = {0, 65536, 131072, 196608, 327680, 458752, 589824};
  const int Kw = KD[z], Nw = ND[z];
  const int nb = blockIdx.x * 32, kb2 = blockIdx.y * 32;
  if (nb >= Nw || kb2 >= Kw) return;
  __shared__ float t[32][33];
  const int x = threadIdx.x, y = threadIdx.y;
  const float* src = wp.p[z];
  for (int i = y; i < 32; i += 8)
    t[i][x] = src[(long long)(kb2 + i) * Nw + nb + x];
  __syncthreads();
  for (int i = y; i < 32; i += 8)
    dst[OFF[z] + (long long)(nb + i) * Kw + kb2 + x] = f2bf(t[x][i]);
}

// ---------------------------------------------------------------------------
// Fused q/k/v projection, 64x64 tiles (z = proj*2 + b, z<6). 1536 blocks.
// ---------------------------------------------------------------------------
__global__ __launch_bounds__(256) void proj64_k(
    const unsigned short* __restrict__ imgT, const unsigned short* __restrict__ wt,
    const float* __restrict__ bq, const float* __restrict__ bk, const float* __restrict__ bv,
    unsigned short* __restrict__ qbf, unsigned short* __restrict__ kbf,
    float* __restrict__ vpp, unsigned short* __restrict__ vtb)
{
  __shared__ __align__(16) unsigned short As[64][72];
  __shared__ __align__(16) unsigned short Bs[64][72];
  const int tid = threadIdx.x;
  const int w = tid >> 6, lane = tid & 63;
  const int lr = lane & 15, quad = lane >> 4;
  const int m0 = blockIdx.x * 64, n0 = blockIdx.y * 64;
  const int z = blockIdx.z, zz = z >> 1, bb = z & 1;
  const int wm = (w >> 1) * 32, wn = (w & 1) * 32;
  const int sr = tid >> 2, sh = (tid & 3) * 16;
  const long long NvCv = (long long)Nv * Cv;

  const float* bias = zz == 0 ? bq : (zz == 1 ? bk : bv);
  const unsigned short* Ab0 = imgT + (long long)z * NvCv + (long long)(m0 + sr) * Cv + sh;
  const unsigned short* Bb0 = wt + (long long)zz * 65536 + (long long)(n0 + sr) * Cv + sh;

  f32x4 acc[2][2];
#pragma unroll
  for (int i = 0; i < 2; ++i)
#pragma unroll
    for (int j = 0; j < 2; ++j) acc[i][j] = (f32x4){0.f, 0.f, 0.f, 0.f};

  uint4 rA0 = *(const uint4*)Ab0, rA1 = *(const uint4*)(Ab0 + 8);
  uint4 rB0 = *(const uint4*)Bb0, rB1 = *(const uint4*)(Bb0 + 8);

  for (int k0 = 0; k0 < Cv; k0 += 64) {
    *(uint4*)&As[sr][sh] = rA0; *(uint4*)&As[sr][sh + 8] = rA1;
    *(uint4*)&Bs[sr][sh] = rB0; *(uint4*)&Bs[sr][sh + 8] = rB1;
    __syncthreads();
    if (k0 + 64 < Cv) {
      rA0 = *(const uint4*)(Ab0 + k0 + 64); rA1 = *(const uint4*)(Ab0 + k0 + 72);
      rB0 = *(const uint4*)(Bb0 + k0 + 64); rB1 = *(const uint4*)(Bb0 + k0 + 72);
    }
#pragma unroll
    for (int ks = 0; ks < 2; ++ks) {
      bf16x8 af[2], bfr[2];
#pragma unroll
      for (int i = 0; i < 2; ++i)
        af[i] = *(const bf16x8*)&As[wm + i * 16 + lr][ks * 32 + quad * 8];
#pragma unroll
      for (int j = 0; j < 2; ++j)
        bfr[j] = *(const bf16x8*)&Bs[wn + j * 16 + lr][ks * 32 + quad * 8];
#pragma unroll
      for (int i = 0; i < 2; ++i)
#pragma unroll
        for (int j = 0; j < 2; ++j)
          acc[i][j] = __builtin_amdgcn_mfma_f32_16x16x32_bf16(af[i], bfr[j], acc[i][j], 0, 0, 0);
    }
    __syncthreads();
  }

#pragma unroll
  for (int j = 0; j < 2; ++j) {
    const int col = n0 + wn + j * 16 + lr;
    const float bvv = bias[col];
#pragma unroll
    for (int i = 0; i < 2; ++i) {
      const int mb = m0 + wm + i * 16 + quad * 4;
      float r[4];
#pragma unroll
      for (int reg = 0; reg < 4; ++reg) r[reg] = acc[i][j][reg] + bvv;
      const long long ob = (long long)bb * NvCv;
      if (zz == 0) {
        // 0.125 (1/SCALE) * log2(e): softmax runs in exp2 domain
#pragma unroll
        for (int reg = 0; reg < 4; ++reg)
          qbf[ob + (long long)(mb + reg) * Cv + col] = f2bf(r[reg] * 0.18033688f);
      } else if (zz == 1) {
#pragma unroll
        for (int reg = 0; reg < 4; ++reg)
          kbf[ob + (long long)(mb + reg) * Cv + col] = f2bf(r[reg]);
      } else {
#pragma unroll
        for (int reg = 0; reg < 4; ++reg)
          vpp[ob + (long long)(mb + reg) * Cv + col] = r[reg];
        uint2 pk;
        pk.x = cvt_pk_bf16(r[0], r[1]);
        pk.y = cvt_pk_bf16(r[2], r[3]);
        *(uint2*)&vtb[ob + (long long)col * Nv + mb] = pk;
      }
    }
  }
}

// ---------------------------------------------------------------------------
// 64x64-tile bf16 MFMA GEMM, register-prefetch K pipeline.
// OM: 0 fp32 [m][n]; 1 bf16 [m][n]; 2 fp32+bf16 dual; 4 fp32 -> [B][C][N].
// ---------------------------------------------------------------------------
template<bool ABF16, int ACT, int RES, int OM>
__global__ __launch_bounds__(256) void mm64_k(
    const void* __restrict__ A, const unsigned short* __restrict__ Bt,
    const float* __restrict__ bias, const float* __restrict__ Res,
    float* __restrict__ outF, unsigned short* __restrict__ outB,
    int M, int Nn, int Kd)
{
  __shared__ __align__(16) unsigned short As[64][72];
  __shared__ __align__(16) unsigned short Bs[64][72];
  const int tid = threadIdx.x;
  const int w = tid >> 6, lane = tid & 63;
  const int lr = lane & 15, quad = lane >> 4;
  const int m0 = blockIdx.x * 64, n0 = blockIdx.y * 64;
  const int wm = (w >> 1) * 32, wn = (w & 1) * 32;
  const int sr = tid >> 2, sh = (tid & 3) * 16;

  f32x4 acc[2][2];
#pragma unroll
  for (int i = 0; i < 2; ++i)
#pragma unroll
    for (int j = 0; j < 2; ++j) acc[i][j] = (f32x4){0.f, 0.f, 0.f, 0.f};

  const long long abase = (long long)(m0 + sr) * Kd + sh;
  const unsigned short* Bb = Bt + (long long)(n0 + sr) * Kd + sh;

  uint4 rA0, rA1, rB0, rB1;
  float4 fA[4];
  if (ABF16) {
    const unsigned short* Ab = (const unsigned short*)A + abase;
    rA0 = *(const uint4*)Ab; rA1 = *(const uint4*)(Ab + 8);
  } else {
    const float* Af = (const float*)A + abase;
    fA[0] = *(const float4*)Af;      fA[1] = *(const float4*)(Af + 4);
    fA[2] = *(const float4*)(Af + 8); fA[3] = *(const float4*)(Af + 12);
  }
  rB0 = *(const uint4*)Bb; rB1 = *(const uint4*)(Bb + 8);

  for (int k0 = 0; k0 < Kd; k0 += 64) {
    if (ABF16) {
      *(uint4*)&As[sr][sh] = rA0; *(uint4*)&As[sr][sh + 8] = rA1;
    } else {
#pragma unroll
      for (int t = 0; t < 2; ++t) {
        uint4 pk;
        pk.x = cvt_pk_bf16(fA[t * 2].x, fA[t * 2].y);
        pk.y = cvt_pk_bf16(fA[t * 2].z, fA[t * 2].w);
        pk.z = cvt_pk_bf16(fA[t * 2 + 1].x, fA[t * 2 + 1].y);
        pk.w = cvt_pk_bf16(fA[t * 2 + 1].z, fA[t * 2 + 1].w);
        *(uint4*)&As[sr][sh + t * 8] = pk;
      }
    }
    *(uint4*)&Bs[sr][sh] = rB0; *(uint4*)&Bs[sr][sh + 8] = rB1;
    __syncthreads();
    if (k0 + 64 < Kd) {
      if (ABF16) {
        const unsigned short* Ab = (const unsigned short*)A + abase + k0 + 64;
        rA0 = *(const uint4*)Ab; rA1 = *(const uint4*)(Ab + 8);
      } else {
        const float* Af = (const float*)A + abase + k0 + 64;
        fA[0] = *(const float4*)Af;      fA[1] = *(const float4*)(Af + 4);
        fA[2] = *(const float4*)(Af + 8); fA[3] = *(const float4*)(Af + 12);
      }
      rB0 = *(const uint4*)(Bb + k0 + 64); rB1 = *(const uint4*)(Bb + k0 + 72);
    }
#pragma unroll
    for (int ks = 0; ks < 2; ++ks) {
      bf16x8 af[2], bfr[2];
#pragma unroll
      for (int i = 0; i < 2; ++i)
        af[i] = *(const bf16x8*)&As[wm + i * 16 + lr][ks * 32 + quad * 8];
#pragma unroll
      for (int j = 0; j < 2; ++j)
        bfr[j] = *(const bf16x8*)&Bs[wn + j * 16 + lr][ks * 32 + quad * 8];
#pragma unroll
      for (int i = 0; i < 2; ++i)
#pragma unroll
        for (int j = 0; j < 2; ++j)
          acc[i][j] = __builtin_amdgcn_mfma_f32_16x16x32_bf16(af[i], bfr[j], acc[i][j], 0, 0, 0);
    }
    __syncthreads();
  }

#pragma unroll
  for (int j = 0; j < 2; ++j) {
    const int col = n0 + wn + j * 16 + lr;
    const float bv = bias[col];
#pragma unroll
    for (int i = 0; i < 2; ++i) {
      const int mb = m0 + wm + i * 16 + quad * 4;
      float r[4];
#pragma unroll
      for (int reg = 0; reg < 4; ++reg) {
        float v = acc[i][j][reg] + bv;
        if (ACT) v = v > 0.f ? v : 0.01f * v;
        if (RES) v += Res[(long long)(mb + reg) * Nn + col];
        r[reg] = v;
      }
      if (OM == 0) {
#pragma unroll
        for (int reg = 0; reg < 4; ++reg)
          outF[(long long)(mb + reg) * Nn + col] = r[reg];
      } else if (OM == 1) {
#pragma unroll
        for (int reg = 0; reg < 4; ++reg)
          outB[(long long)(mb + reg) * Nn + col] = f2bf(r[reg]);
      } else if (OM == 2) {   // dual: fp32 + bf16 copies of [m][n]
#pragma unroll
        for (int reg = 0; reg < 4; ++reg) {
          outF[(long long)(mb + reg) * Nn + col] = r[reg];
          outB[(long long)(mb + reg) * Nn + col] = f2bf(r[reg]);
        }
      } else {  // OM == 4: fp32 [B][C][N], m flattened over (b,n)
        const float4 st = {r[0], r[1], r[2], r[3]};
        *(float4*)&outF[((long long)((mb >> 12) * Cv + col)) * Nv + (mb & 4095)] = st;
      }
    }
  }
}

// ---------------------------------------------------------------------------
// 32-row-tile GEMM for the N=256/K=512 MLPs: grid (M/32, N/64) = 1024 blocks
// (4/CU vs 2/CU at 64-row tiles). bf16 A only. Same OM codes as mm64_k.
// ---------------------------------------------------------------------------
template<int ACT, int RES, int OM>
__global__ __launch_bounds__(256) void mm32_k(
    const unsigned short* __restrict__ A, const unsigned short* __restrict__ Bt,
    const float* __restrict__ bias, const float* __restrict__ Res,
    float* __restrict__ outF, unsigned short* __restrict__ outB,
    int Nn, int Kd)
{
  __shared__ __align__(16) unsigned short As[32][72];
  __shared__ __align__(16) unsigned short Bs[64][72];
  const int tid = threadIdx.x;
  const int w = tid >> 6, lane = tid & 63;
  const int lr = lane & 15, quad = lane >> 4;
  const int m0 = blockIdx.x * 32, n0 = blockIdx.y * 64;
  const int wm = (w >> 1) * 16, wn = (w & 1) * 32;
  const int srA = tid >> 3, shA = (tid & 7) * 8;
  const int srB = tid >> 2, shB = (tid & 3) * 16;

  f32x4 acc[2];
  acc[0] = (f32x4){0.f, 0.f, 0.f, 0.f};
  acc[1] = (f32x4){0.f, 0.f, 0.f, 0.f};

  const unsigned short* Ab0 = A + (long long)(m0 + srA) * Kd + shA;
  const unsigned short* Bb  = Bt + (long long)(n0 + srB) * Kd + shB;

  uint4 rA = *(const uint4*)Ab0;
  uint4 rB0 = *(const uint4*)Bb, rB1 = *(const uint4*)(Bb + 8);

  for (int k0 = 0; k0 < Kd; k0 += 64) {
    *(uint4*)&As[srA][shA] = rA;
    *(uint4*)&Bs[srB][shB] = rB0; *(uint4*)&Bs[srB][shB + 8] = rB1;
    __syncthreads();
    if (k0 + 64 < Kd) {
      rA = *(const uint4*)(Ab0 + k0 + 64);
      rB0 = *(const uint4*)(Bb + k0 + 64); rB1 = *(const uint4*)(Bb + k0 + 72);
    }
#pragma unroll
    for (int ks = 0; ks < 2; ++ks) {
      const bf16x8 af = *(const bf16x8*)&As[wm + lr][ks * 32 + quad * 8];
      bf16x8 bfr[2];
#pragma unroll
      for (int j = 0; j < 2; ++j)
        bfr[j] = *(const bf16x8*)&Bs[wn + j * 16 + lr][ks * 32 + quad * 8];
#pragma unroll
      for (int j = 0; j < 2; ++j)
        acc[j] = __builtin_amdgcn_mfma_f32_16x16x32_bf16(af, bfr[j], acc[j], 0, 0, 0);
    }
    __syncthreads();
  }

#pragma unroll
  for (int j = 0; j < 2; ++j) {
    const int col = n0 + wn + j * 16 + lr;
    const float bv = bias[col];
    const int mb = m0 + wm + quad * 4;
    float r[4];
#pragma unroll
    for (int reg = 0; reg < 4; ++reg) {
      float v = acc[j][reg] + bv;
      if (ACT) v = v > 0.f ? v : 0.01f * v;
      if (RES) v += Res[(long long)(mb + reg) * Nn + col];
      r[reg] = v;
    }
    if (OM == 0) {
#pragma unroll
      for (int reg = 0; reg < 4; ++reg)
        outF[(long long)(mb + reg) * Nn + col] = r[reg];
    } else if (OM == 1) {
#pragma unroll
      for (int reg = 0; reg < 4; ++reg)
        outB[(long long)(mb + reg) * Nn + col] = f2bf(r[reg]);
    } else if (OM == 2) {   // dual: fp32 + bf16 copies of [m][n]
#pragma unroll
      for (int reg = 0; reg < 4; ++reg) {
        outF[(long long)(mb + reg) * Nn + col] = r[reg];
        outB[(long long)(mb + reg) * Nn + col] = f2bf(r[reg]);
      }
    } else {  // OM == 4: fp32 [B][C][N], m flattened over (b,n)
      const float4 st = {r[0], r[1], r[2], r[3]};
      *(float4*)&outF[((long long)((mb >> 12) * Cv + col)) * Nv + (mb & 4095)] = st;
    }
  }
}

// ---------------------------------------------------------------------------
// Cluster centers (accumulate only; attn normalizes on load)
// ---------------------------------------------------------------------------
__global__ __launch_bounds__(256) void center_accum(
    const unsigned short* __restrict__ kb, const int* __restrict__ labels,
    float* __restrict__ cent, float* __restrict__ cnts)
{
  __shared__ int lab_s[512];
  const int bx = blockIdx.x;           // Bv*Kv*8 blocks
  const int chunk = bx & 7;
  const int kk = (bx >> 3) & 15;
  const int b = bx >> 7;
  const int c = threadIdx.x;
  const int nbase = chunk * 512;
  for (int i = threadIdx.x; i < 512; i += 256) lab_s[i] = labels[b * Nv + nbase + i];
  __syncthreads();
  float acc = 0.f;
  int cnt = 0;
#pragma unroll 4
  for (int i = 0; i < 512; ++i) {
    if (lab_s[i] == kk) {              // wave-uniform branch on LDS value
      acc += bf2f(kb[(long long)(b * Nv + nbase + i) * Cv + c]);
      ++cnt;
    }
  }
  atomicAdd(&cent[(b * Kv + kk) * Cv + c], acc);
  if (c == 0) atomicAdd(&cnts[b * Kv + kk], (float)cnt);
}

// ---------------------------------------------------------------------------
// MFMA flash attention, split-m x2, LDS 32000B overlays (R12) + pc prefetch
// depth 2 (pcA/pcB ping-pong; NO launch-bounds cap -> no spill).
// p = exp2(s), no shift. cvt_pk P pack. Partials: opart/lpart as before.
// ---------------------------------------------------------------------------
__global__ __launch_bounds__(256) void attn_k(
    const unsigned short* __restrict__ qb, const unsigned short* __restrict__ kb,
    const unsigned short* __restrict__ vtb, const float* __restrict__ cent,
    const float* __restrict__ cnts, const int* __restrict__ labels,
    const float* __restrict__ pc, float* __restrict__ opart, float* __restrict__ lpart)
{
  __shared__ __align__(16) unsigned short q_s[64][72];   // q rows, then P tiles
  __shared__ __align__(16) unsigned short k_s[64][72];   // centers, then K tile
  __shared__ __align__(16) unsigned short vt_s[64][72];
  __shared__ float ac_s[64][17];

  const int tid = threadIdx.x;
  const int lane = tid & 63, w = tid >> 6;
  const int lr = lane & 15, quad = lane >> 4;
  const int bx = blockIdx.x;
  const int qt = bx & 63, h = (bx >> 6) & 3, b = (bx >> 8) & 1;
  const int part = bx >> 9;
  const int n0 = qt * 64;
  const int mbase = part * 2048;
  const int sr2 = tid >> 2, so2 = (tid & 3) * 16;
  const int row_l = w * 16 + quad * 4;
  const long long pcb = (long long)b * Nv * Nv;

  // ---- prologue: stage q + normalized centers (centers live in k_s)
  {
    const unsigned short* src = qb + ((long long)(b * Nv + n0 + sr2)) * Cv + h * HDv + so2;
    *(uint4*)&q_s[sr2][so2] = *(const uint4*)src;
    *(uint4*)&q_s[sr2][so2 + 8] = *(const uint4*)(src + 8);
  }
  float* c_s = (float*)&k_s[0][0];   // [16][68] floats = 4352 B
  for (int idx = tid; idx < Kv * HDv; idx += 256) {
    const int kk = idx >> 6, d = idx & 63;
    c_s[kk * 68 + d] = cent[((long long)(b * Kv + kk)) * Cv + h * HDv + d]
                       / (cnts[b * Kv + kk] + 1e-6f);
  }

  // issue tile-0 k/v + pc(0)/pc(1) + labels while the block syncs
  uint4 ka0, ka1, va0, va1;
  float pcA[4][4], pcB[4][4];
  int labm1[4], labq[4];
  {
    const long long ks = ((long long)(b * Nv + mbase + sr2)) * Cv + h * HDv + so2;
    ka0 = *(const uint4*)(kb + ks); ka1 = *(const uint4*)(kb + ks + 8);
    const long long vs = ((long long)(b * Cv + h * HDv + sr2)) * Nv + mbase + so2;
    va0 = *(const uint4*)(vtb + vs); va1 = *(const uint4*)(vtb + vs + 8);
  }
#pragma unroll
  for (int sub = 0; sub < 4; ++sub) {
    labm1[sub] = labels[b * Nv + mbase + sub * 16 + lr];
#pragma unroll
    for (int reg = 0; reg < 4; ++reg) {
      pcA[sub][reg] = pc[pcb + (long long)(n0 + row_l + reg) * Nv + mbase + sub * 16 + lr];
      pcB[sub][reg] = pc[pcb + (long long)(n0 + row_l + reg) * Nv + mbase + 64 + sub * 16 + lr];
    }
  }
#pragma unroll
  for (int reg = 0; reg < 4; ++reg) labq[reg] = labels[b * Nv + n0 + row_l + reg];

  __syncthreads();               // q_s, c_s visible
  // ac_s[r][k] = (q_r scaled) . center_k
  for (int idx = tid; idx < 64 * Kv; idx += 256) {
    const int r = idx >> 4, kk = idx & 15;
    float s = 0.f;
#pragma unroll
    for (int d = 0; d < HDv; ++d) s += bf2f(q_s[r][d]) * c_s[kk * 68 + d];
    ac_s[r][kk] = s;
  }
  const bf16x8 qa0 = *(const bf16x8*)&q_s[w * 16 + lr][quad * 8];
  const bf16x8 qa1 = *(const bf16x8*)&q_s[w * 16 + lr][32 + quad * 8];
  __syncthreads();               // ac_s visible; all q_s/c_s reads done

  // tile-0 acg gather (register-resident select operand)
  float acg[4][4];
#pragma unroll
  for (int sub = 0; sub < 4; ++sub)
#pragma unroll
    for (int reg = 0; reg < 4; ++reg)
      acg[sub][reg] = ac_s[row_l + reg][labm1[sub]];

  // stage tile 0 from regs (k_s stops being centers here)
  *(uint4*)&k_s[sr2][so2] = ka0; *(uint4*)&k_s[sr2][so2 + 8] = ka1;
  *(uint4*)&vt_s[sr2][so2] = va0; *(uint4*)&vt_s[sr2][so2 + 8] = va1;
  __syncthreads();               // tile 0 visible

  f32x4 oacc[4];
#pragma unroll
  for (int s2 = 0; s2 < 4; ++s2) oacc[s2] = (f32x4){0.f, 0.f, 0.f, 0.f};
  float lrow[4] = {0.f, 0.f, 0.f, 0.f};

#define ATTN_TILE(PCREG)                                                        \
  {                                                                             \
    const int m0 = mbase + t * 64;                                              \
    const bool has1 = (t < 31);                                                 \
    const bool has2 = (t < 30);                                                 \
    if (has1) {                                                                 \
      const long long ks = ((long long)(b * Nv + m0 + 64 + sr2)) * Cv + h * HDv + so2; \
      ka0 = *(const uint4*)(kb + ks); ka1 = *(const uint4*)(kb + ks + 8);       \
      const long long vs = ((long long)(b * Cv + h * HDv + sr2)) * Nv + m0 + 64 + so2; \
      va0 = *(const uint4*)(vtb + vs); va1 = *(const uint4*)(vtb + vs + 8);     \
    }                                                                           \
    f32x4 sacc[4];                                                              \
    __builtin_amdgcn_s_setprio(1);                                              \
    _Pragma("unroll")                                                           \
    for (int sub = 0; sub < 4; ++sub) {                                         \
      const bf16x8 kf0 = *(const bf16x8*)&k_s[sub * 16 + lr][quad * 8];         \
      const bf16x8 kf1 = *(const bf16x8*)&k_s[sub * 16 + lr][32 + quad * 8];    \
      f32x4 s = (f32x4){0.f, 0.f, 0.f, 0.f};                                    \
      s = __builtin_amdgcn_mfma_f32_16x16x32_bf16(qa0, kf0, s, 0, 0, 0);        \
      s = __builtin_amdgcn_mfma_f32_16x16x32_bf16(qa1, kf1, s, 0, 0, 0);        \
      sacc[sub] = s;                                                            \
    }                                                                           \
    __builtin_amdgcn_s_setprio(0);                                              \
    _Pragma("unroll")                                                           \
    for (int sub = 0; sub < 4; ++sub) {                                         \
      float p4[4];                                                              \
      _Pragma("unroll")                                                         \
      for (int reg = 0; reg < 4; ++reg) {                                       \
        const float s = (labm1[sub] == labq[reg]) ? sacc[sub][reg]              \
                                                  : acg[sub][reg] * PCREG[sub][reg]; \
        const float p = exp2_raw(s);                                            \
        lrow[reg] += p;                                                         \
        p4[reg] = p;                                                            \
      }                                                                         \
      const unsigned int pk01 = cvt_pk_bf16(p4[0], p4[1]);                      \
      const unsigned int pk23 = cvt_pk_bf16(p4[2], p4[3]);                      \
      unsigned short* pp = &q_s[w * 16 + quad * 4][sub * 16 + lr];              \
      pp[0]   = (unsigned short)pk01;                                           \
      pp[72]  = (unsigned short)(pk01 >> 16);                                   \
      pp[144] = (unsigned short)pk23;                                           \
      pp[216] = (unsigned short)(pk23 >> 16);                                   \
    }                                                                           \
    if (has1) {                                                                 \
      _Pragma("unroll")                                                         \
      for (int sub = 0; sub < 4; ++sub)                                         \
        labm1[sub] = labels[b * Nv + m0 + 64 + sub * 16 + lr];                  \
    }                                                                           \
    if (has2) {                                                                 \
      _Pragma("unroll")                                                         \
      for (int sub = 0; sub < 4; ++sub) {                                       \
        _Pragma("unroll")                                                       \
        for (int reg = 0; reg < 4; ++reg)                                       \
          PCREG[sub][reg] = pc[pcb + (long long)(n0 + row_l + reg) * Nv + m0 + 128 + sub * 16 + lr]; \
      }                                                                         \
    }                                                                           \
    const bf16x8 pa0 = *(const bf16x8*)&q_s[w * 16 + lr][quad * 8];             \
    const bf16x8 pa1 = *(const bf16x8*)&q_s[w * 16 + lr][32 + quad * 8];        \
    __builtin_amdgcn_s_setprio(1);                                              \
    _Pragma("unroll")                                                           \
    for (int sub = 0; sub < 4; ++sub) {                                         \
      const bf16x8 vb0 = *(const bf16x8*)&vt_s[sub * 16 + lr][quad * 8];        \
      const bf16x8 vb1 = *(const bf16x8*)&vt_s[sub * 16 + lr][32 + quad * 8];   \
      oacc[sub] = __builtin_amdgcn_mfma_f32_16x16x32_bf16(pa0, vb0, oacc[sub], 0, 0, 0); \
      oacc[sub] = __builtin_amdgcn_mfma_f32_16x16x32_bf16(pa1, vb1, oacc[sub], 0, 0, 0); \
    }                                                                           \
    __builtin_amdgcn_s_setprio(0);                                              \
    if (has1) {                                                                 \
      _Pragma("unroll")                                                         \
      for (int sub = 0; sub < 4; ++sub) {                                       \
        _Pragma("unroll")                                                       \
        for (int reg = 0; reg < 4; ++reg)                                       \
          acg[sub][reg] = ac_s[row_l + reg][labm1[sub]];                        \
      }                                                                         \
    }                                                                           \
    __syncthreads();                                                            \
    if (has1) {                                                                 \
      *(uint4*)&k_s[sr2][so2] = ka0; *(uint4*)&k_s[sr2][so2 + 8] = ka1;         \
      *(uint4*)&vt_s[sr2][so2] = va0; *(uint4*)&vt_s[sr2][so2 + 8] = va1;       \
    }                                                                           \
    __syncthreads();                                                            \
    ++t;                                                                        \
  }

  int t = 0;
  for (int it = 0; it < 16; ++it) {
    ATTN_TILE(pcA)               // even tile
    ATTN_TILE(pcB)               // odd tile
  }
#undef ATTN_TILE

  // epilogue: partial sums (no normalization; combine_k divides)
#pragma unroll
  for (int reg = 0; reg < 4; ++reg) {
    float l = lrow[reg];
    l += __shfl_xor(l, 1); l += __shfl_xor(l, 2);
    l += __shfl_xor(l, 4); l += __shfl_xor(l, 8);
    const int row = n0 + row_l + reg;
    const long long obase = (long long)part * 2097152 + ((long long)(b * Nv + row)) * Cv + h * HDv;
#pragma unroll
    for (int sub = 0; sub < 4; ++sub)
      opart[obase + sub * 16 + lr] = oacc[sub][reg];
    if (lr == 0)
      lpart[part * 32768 + (b * 4 + h) * 4096 + row] = l;
  }
}

// ---------------------------------------------------------------------------
// Combine split-m partials: aob = (o0+o1)/(l0+l1), bf16
// ---------------------------------------------------------------------------
__global__ __launch_bounds__(256) void combine_k(
    const float* __restrict__ op, const float* __restrict__ lp,
    unsigned short* __restrict__ aob)
{
  const long long i4 = ((long long)blockIdx.x * 256 + threadIdx.x) * 4;
  const int c = (int)(i4 & 255), n = (int)((i4 >> 8) & 4095), b = (int)(i4 >> 20);
  const int h = c >> 6;
  const float l = lp[(b * 4 + h) * 4096 + n] + lp[32768 + (b * 4 + h) * 4096 + n];
  const float inv = 1.f / l;
  const float4 a = *(const float4*)&op[i4];
  const float4 d = *(const float4*)&op[2097152 + i4];
  uint2 pk;
  pk.x = cvt_pk_bf16((a.x + d.x) * inv, (a.y + d.y) * inv);
  pk.y = cvt_pk_bf16((a.z + d.z) * inv, (a.w + d.w) * inv);
  *(uint2*)&aob[i4] = pk;
}

// ---------------------------------------------------------------------------
extern "C" void kernel_launch(void* const* d_in, const int* in_sizes, int n_in,
                              void* d_out, int out_size, void* d_ws, size_t ws_size,
                              hipStream_t stream)
{
  const float* q_img = (const float*)d_in[0];
  const float* k_img = (const float*)d_in[1];
  const float* v_img = (const float*)d_in[2];
  const int* labels  = (const int*)d_in[3];
  const float* pc    = (const float*)d_in[4];
  const float* Wq  = (const float*)d_in[5];  const float* bq  = (const float*)d_in[6];
  const float* Wk  = (const float*)d_in[7];  const float* bk  = (const float*)d_in[8];
  const float* Wv  = (const float*)d_in[9];  const float* bv  = (const float*)d_in[10];
  const float* W11 = (const float*)d_in[11]; const float* b11 = (const float*)d_in[12];
  const float* W12 = (const float*)d_in[13]; const float* b12 = (const float*)d_in[14];
  const float* W21 = (const float*)d_in[15]; const float* b21 = (const float*)d_in[16];
  const float* W22 = (const float*)d_in[17]; const float* b22 = (const float*)d_in[18];
  float* outp = (float*)d_out;

  const long long SZ = (long long)Bv * Nv * Cv;     // 2,097,152
  // fp32 region (~32.3 MB)
  float* ws    = (float*)d_ws;
  float* vpp   = ws;                       // v proj fp32
  float* rs1   = vpp + SZ;                 // MLP1 out fp32
  float* opart = rs1 + SZ;                 // attn partials [2][B][N][C]
  float* lpart = opart + 2 * SZ;           // [2][B][NH][N]
  float* cent  = lpart + 65536;            // [B][K][C]
  float* cnts  = cent + Bv * Kv * Cv;      // [B][K]
  // bf16 region (~25.4 MB)
  unsigned short* wt   = (unsigned short*)(cnts + Bv * Kv);
  unsigned short* qbf  = wt + 720896;      // [B][N][C] pre-scaled 0.125*log2e
  unsigned short* kbf  = qbf + SZ;
  unsigned short* vtb  = kbf + SZ;         // [B][C][N]
  unsigned short* aob  = vtb + SZ;         // attn out bf16; later rs1-bf16
  unsigned short* h1b  = aob + SZ;         // MLP hidden [2N][2C]
  unsigned short* imgT = aob;              // overlay (dead after proj)

  // prep (wt_k z==7 zeros cent+cnts)
  imgt_k<<<dim3(Nv / 32, Cv / 32, 6), dim3(32, 8), 0, stream>>>(q_img, k_img, v_img, imgT);
  WP wp = {{Wq, Wk, Wv, W11, W12, W21, W22}};
  wt_k<<<dim3(16, 16, 8), dim3(32, 8), 0, stream>>>(wp, wt, cent, Bv * Kv * Cv + Bv * Kv);

  // fused q/k/v projections (64x64 tiles, 1536 blocks = 6/CU)
  proj64_k<<<dim3(64, 4, 6), 256, 0, stream>>>(imgT, wt, bq, bk, bv, qbf, kbf, vpp, vtb);

  // cluster centers (normalization folded into attn)
  center_accum<<<dim3(Bv * Kv * 8), 256, 0, stream>>>(kbf, labels, cent, cnts);

  // attention (split-m x2) + combine
  attn_k<<<dim3(1024), 256, 0, stream>>>(qbf, kbf, vtb, cent, cnts, labels, pc, opart, lpart);
  combine_k<<<dim3(2048), 256, 0, stream>>>(opart, lpart, aob);

  // MLP1: h1 = leaky(aob@W11+b11); rs1 = vpp + h1@W12+b12 (fp32 + bf16->aob)
  mm64_k<true, 1, 0, 1><<<dim3(128, 8), 256, 0, stream>>>(
      aob, wt + 196608, b11, nullptr, nullptr, h1b, 2 * Nv, 2 * Cv, Cv);
  mm32_k<0, 1, 2><<<dim3(256, 4), 256, 0, stream>>>(
      h1b, wt + 327680, b12, vpp, rs1, aob, Cv, 2 * Cv);

  // MLP2: h2 = leaky(rs1b@W21+b21); out = rs1 + h2@W22+b22 -> [B][C][H][W]
  mm64_k<true, 1, 0, 1><<<dim3(128, 8), 256, 0, stream>>>(
      aob, wt + 458752, b21, nullptr, nullptr, h1b, 2 * Nv, 2 * Cv, Cv);
  mm32_k<0, 1, 4><<<dim3(256, 4), 256, 0, stream>>>(
      h1b, wt + 589824, b22, rs1, outp, nullptr, Cv, 2 * Cv);
}

// Round 8
// 396.053 us; speedup vs baseline: 1.0327x; 1.0327x over previous
//
#include <hip/hip_runtime.h>
#include <stdint.h>

#define Bv 2
#define Cv 256
#define Nv 4096
#define NHv 4
#define HDv 64
#define Kv 16

// R14: attn = R12 body (best measured: 120.2 us attn / 396.2 total) with the
// two main-loop __syncthreads replaced by lgkmcnt-only barriers
// (s_waitcnt lgkmcnt(0) + raw s_barrier). __syncthreads drains vmcnt(0),
// force-waiting the pc/k/v prefetch at every barrier; the raw barrier keeps
// global loads in flight across tiles (compiler still inserts data-dep
// vmcnt waits at the consume points). LDS protocol ordering (k_s/vt_s/ac_s)
// is fully covered by lgkmcnt. mm32 experiment reverted (R12 mm64 grids).

typedef __attribute__((ext_vector_type(8))) short bf16x8;
typedef __attribute__((ext_vector_type(4))) float f32x4;

__device__ __forceinline__ float bf2f(unsigned short u) {
  union { unsigned int i; float f; } x; x.i = ((unsigned int)u) << 16; return x.f;
}
__device__ __forceinline__ unsigned short f2bf(float f) {
  union { float f; unsigned int i; } x; x.f = f;
  unsigned int r = x.i + 0x7FFF + ((x.i >> 16) & 1);   // RNE
  return (unsigned short)(r >> 16);
}
__device__ __forceinline__ unsigned int cvt_pk_bf16(float lo, float hi) {
  unsigned int r;
  asm("v_cvt_pk_bf16_f32 %0, %1, %2" : "=v"(r) : "v"(lo), "v"(hi));
  return r;
}
__device__ __forceinline__ float exp2_raw(float x) {
  float r;
  asm("v_exp_f32 %0, %1" : "=v"(r) : "v"(x));
  return r;
}
// Barrier that waits LDS ops only -- does NOT drain vmcnt (global loads stay
// in flight across the barrier; compiler inserts vmcnt waits at consume).
__device__ __forceinline__ void barrier_lds() {
  asm volatile("s_waitcnt lgkmcnt(0)" ::: "memory");
  __builtin_amdgcn_s_barrier();
}

// ---------------------------------------------------------------------------
// Prep 1: img [b][c][n] fp32 -> imgT [z][n][c] bf16  (z = img*2 + b, z<6)
// ---------------------------------------------------------------------------
__global__ __launch_bounds__(256) void imgt_k(
    const float* __restrict__ qi, const float* __restrict__ ki,
    const float* __restrict__ vi, unsigned short* __restrict__ dst)
{
  const int z = blockIdx.z;
  const float* src = (z < 2 ? qi : (z < 4 ? ki : vi)) + (long long)(z & 1) * Cv * Nv;
  unsigned short* out = dst + (long long)z * Nv * Cv;
  __shared__ float t[32][33];
  const int x = threadIdx.x, y = threadIdx.y;
  const int n0 = blockIdx.x * 32, c0 = blockIdx.y * 32;
  for (int i = y; i < 32; i += 8)
    t[i][x] = src[(long long)(c0 + i) * Nv + n0 + x];
  __syncthreads();
  for (int i = y; i < 32; i += 8)
    out[(long long)(n0 + i) * Cv + c0 + x] = f2bf(t[x][i]);
}

// ---------------------------------------------------------------------------
// Prep 2: W [k][n] fp32 -> Wt [n][k] bf16 (z<7); z==7 zeros cent/cnts
// ---------------------------------------------------------------------------
struct WP { const float* p[7]; };

__global__ __launch_bounds__(256) void wt_k(WP wp, unsigned short* __restrict__ dst,
                                            float* __restrict__ zp, int zn)
{
  const int z = blockIdx.z;
  if (z == 7) {
    const int idx = (blockIdx.y * 16 + blockIdx.x) * 256 + threadIdx.y * 32 + threadIdx.x;
    if (idx < zn) zp[idx] = 0.f;
    return;
  }
  const int KD[7] = {256, 256, 256, 256, 512, 256, 512};
  const int ND[7] = {256, 256, 256, 512, 256, 512, 256};
  const long long OFF[7] = {0, 65536, 131072, 196608, 327680, 458752, 589824};
  const int Kw = KD[z], Nw = ND[z];
  const int nb = blockIdx.x * 32, kb2 = blockIdx.y * 32;
  if (nb >= Nw || kb2 >= Kw) return;
  __shared__ float t[32][33];
  const int x = threadIdx.x, y = threadIdx.y;
  const float* src = wp.p[z];
  for (int i = y; i < 32; i += 8)
    t[i][x] = src[(long long)(kb2 + i) * Nw + nb + x];
  __syncthreads();
  for (int i = y; i < 32; i += 8)
    dst[OFF[z] + (long long)(nb + i) * Kw + kb2 + x] = f2bf(t[x][i]);
}

// ---------------------------------------------------------------------------
// Fused q/k/v projection, 64x64 tiles (z = proj*2 + b, z<6). 1536 blocks.
// ---------------------------------------------------------------------------
__global__ __launch_bounds__(256) void proj64_k(
    const unsigned short* __restrict__ imgT, const unsigned short* __restrict__ wt,
    const float* __restrict__ bq, const float* __restrict__ bk, const float* __restrict__ bv,
    unsigned short* __restrict__ qbf, unsigned short* __restrict__ kbf,
    float* __restrict__ vpp, unsigned short* __restrict__ vtb)
{
  __shared__ __align__(16) unsigned short As[64][72];
  __shared__ __align__(16) unsigned short Bs[64][72];
  const int tid = threadIdx.x;
  const int w = tid >> 6, lane = tid & 63;
  const int lr = lane & 15, quad = lane >> 4;
  const int m0 = blockIdx.x * 64, n0 = blockIdx.y * 64;
  const int z = blockIdx.z, zz = z >> 1, bb = z & 1;
  const int wm = (w >> 1) * 32, wn = (w & 1) * 32;
  const int sr = tid >> 2, sh = (tid & 3) * 16;
  const long long NvCv = (long long)Nv * Cv;

  const float* bias = zz == 0 ? bq : (zz == 1 ? bk : bv);
  const unsigned short* Ab0 = imgT + (long long)z * NvCv + (long long)(m0 + sr) * Cv + sh;
  const unsigned short* Bb0 = wt + (long long)zz * 65536 + (long long)(n0 + sr) * Cv + sh;

  f32x4 acc[2][2];
#pragma unroll
  for (int i = 0; i < 2; ++i)
#pragma unroll
    for (int j = 0; j < 2; ++j) acc[i][j] = (f32x4){0.f, 0.f, 0.f, 0.f};

  uint4 rA0 = *(const uint4*)Ab0, rA1 = *(const uint4*)(Ab0 + 8);
  uint4 rB0 = *(const uint4*)Bb0, rB1 = *(const uint4*)(Bb0 + 8);

  for (int k0 = 0; k0 < Cv; k0 += 64) {
    *(uint4*)&As[sr][sh] = rA0; *(uint4*)&As[sr][sh + 8] = rA1;
    *(uint4*)&Bs[sr][sh] = rB0; *(uint4*)&Bs[sr][sh + 8] = rB1;
    __syncthreads();
    if (k0 + 64 < Cv) {
      rA0 = *(const uint4*)(Ab0 + k0 + 64); rA1 = *(const uint4*)(Ab0 + k0 + 72);
      rB0 = *(const uint4*)(Bb0 + k0 + 64); rB1 = *(const uint4*)(Bb0 + k0 + 72);
    }
#pragma unroll
    for (int ks = 0; ks < 2; ++ks) {
      bf16x8 af[2], bfr[2];
#pragma unroll
      for (int i = 0; i < 2; ++i)
        af[i] = *(const bf16x8*)&As[wm + i * 16 + lr][ks * 32 + quad * 8];
#pragma unroll
      for (int j = 0; j < 2; ++j)
        bfr[j] = *(const bf16x8*)&Bs[wn + j * 16 + lr][ks * 32 + quad * 8];
#pragma unroll
      for (int i = 0; i < 2; ++i)
#pragma unroll
        for (int j = 0; j < 2; ++j)
          acc[i][j] = __builtin_amdgcn_mfma_f32_16x16x32_bf16(af[i], bfr[j], acc[i][j], 0, 0, 0);
    }
    __syncthreads();
  }

#pragma unroll
  for (int j = 0; j < 2; ++j) {
    const int col = n0 + wn + j * 16 + lr;
    const float bvv = bias[col];
#pragma unroll
    for (int i = 0; i < 2; ++i) {
      const int mb = m0 + wm + i * 16 + quad * 4;
      float r[4];
#pragma unroll
      for (int reg = 0; reg < 4; ++reg) r[reg] = acc[i][j][reg] + bvv;
      const long long ob = (long long)bb * NvCv;
      if (zz == 0) {
        // 0.125 (1/SCALE) * log2(e): softmax runs in exp2 domain
#pragma unroll
        for (int reg = 0; reg < 4; ++reg)
          qbf[ob + (long long)(mb + reg) * Cv + col] = f2bf(r[reg] * 0.18033688f);
      } else if (zz == 1) {
#pragma unroll
        for (int reg = 0; reg < 4; ++reg)
          kbf[ob + (long long)(mb + reg) * Cv + col] = f2bf(r[reg]);
      } else {
#pragma unroll
        for (int reg = 0; reg < 4; ++reg)
          vpp[ob + (long long)(mb + reg) * Cv + col] = r[reg];
        uint2 pk;
        pk.x = cvt_pk_bf16(r[0], r[1]);
        pk.y = cvt_pk_bf16(r[2], r[3]);
        *(uint2*)&vtb[ob + (long long)col * Nv + mb] = pk;
      }
    }
  }
}

// ---------------------------------------------------------------------------
// 64x64-tile bf16 MFMA GEMM, register-prefetch K pipeline.
// OM: 0 fp32 [m][n]; 1 bf16 [m][n]; 2 fp32+bf16 dual; 4 fp32 -> [B][C][N].
// ---------------------------------------------------------------------------
template<bool ABF16, int ACT, int RES, int OM>
__global__ __launch_bounds__(256) void mm64_k(
    const void* __restrict__ A, const unsigned short* __restrict__ Bt,
    const float* __restrict__ bias, const float* __restrict__ Res,
    float* __restrict__ outF, unsigned short* __restrict__ outB,
    int M, int Nn, int Kd)
{
  __shared__ __align__(16) unsigned short As[64][72];
  __shared__ __align__(16) unsigned short Bs[64][72];
  const int tid = threadIdx.x;
  const int w = tid >> 6, lane = tid & 63;
  const int lr = lane & 15, quad = lane >> 4;
  const int m0 = blockIdx.x * 64, n0 = blockIdx.y * 64;
  const int wm = (w >> 1) * 32, wn = (w & 1) * 32;
  const int sr = tid >> 2, sh = (tid & 3) * 16;

  f32x4 acc[2][2];
#pragma unroll
  for (int i = 0; i < 2; ++i)
#pragma unroll
    for (int j = 0; j < 2; ++j) acc[i][j] = (f32x4){0.f, 0.f, 0.f, 0.f};

  const long long abase = (long long)(m0 + sr) * Kd + sh;
  const unsigned short* Bb = Bt + (long long)(n0 + sr) * Kd + sh;

  uint4 rA0, rA1, rB0, rB1;
  float4 fA[4];
  if (ABF16) {
    const unsigned short* Ab = (const unsigned short*)A + abase;
    rA0 = *(const uint4*)Ab; rA1 = *(const uint4*)(Ab + 8);
  } else {
    const float* Af = (const float*)A + abase;
    fA[0] = *(const float4*)Af;      fA[1] = *(const float4*)(Af + 4);
    fA[2] = *(const float4*)(Af + 8); fA[3] = *(const float4*)(Af + 12);
  }
  rB0 = *(const uint4*)Bb; rB1 = *(const uint4*)(Bb + 8);

  for (int k0 = 0; k0 < Kd; k0 += 64) {
    if (ABF16) {
      *(uint4*)&As[sr][sh] = rA0; *(uint4*)&As[sr][sh + 8] = rA1;
    } else {
#pragma unroll
      for (int t = 0; t < 2; ++t) {
        uint4 pk;
        pk.x = cvt_pk_bf16(fA[t * 2].x, fA[t * 2].y);
        pk.y = cvt_pk_bf16(fA[t * 2].z, fA[t * 2].w);
        pk.z = cvt_pk_bf16(fA[t * 2 + 1].x, fA[t * 2 + 1].y);
        pk.w = cvt_pk_bf16(fA[t * 2 + 1].z, fA[t * 2 + 1].w);
        *(uint4*)&As[sr][sh + t * 8] = pk;
      }
    }
    *(uint4*)&Bs[sr][sh] = rB0; *(uint4*)&Bs[sr][sh + 8] = rB1;
    __syncthreads();
    if (k0 + 64 < Kd) {
      if (ABF16) {
        const unsigned short* Ab = (const unsigned short*)A + abase + k0 + 64;
        rA0 = *(const uint4*)Ab; rA1 = *(const uint4*)(Ab + 8);
      } else {
        const float* Af = (const float*)A + abase + k0 + 64;
        fA[0] = *(const float4*)Af;      fA[1] = *(const float4*)(Af + 4);
        fA[2] = *(const float4*)(Af + 8); fA[3] = *(const float4*)(Af + 12);
      }
      rB0 = *(const uint4*)(Bb + k0 + 64); rB1 = *(const uint4*)(Bb + k0 + 72);
    }
#pragma unroll
    for (int ks = 0; ks < 2; ++ks) {
      bf16x8 af[2], bfr[2];
#pragma unroll
      for (int i = 0; i < 2; ++i)
        af[i] = *(const bf16x8*)&As[wm + i * 16 + lr][ks * 32 + quad * 8];
#pragma unroll
      for (int j = 0; j < 2; ++j)
        bfr[j] = *(const bf16x8*)&Bs[wn + j * 16 + lr][ks * 32 + quad * 8];
#pragma unroll
      for (int i = 0; i < 2; ++i)
#pragma unroll
        for (int j = 0; j < 2; ++j)
          acc[i][j] = __builtin_amdgcn_mfma_f32_16x16x32_bf16(af[i], bfr[j], acc[i][j], 0, 0, 0);
    }
    __syncthreads();
  }

#pragma unroll
  for (int j = 0; j < 2; ++j) {
    const int col = n0 + wn + j * 16 + lr;
    const float bv = bias[col];
#pragma unroll
    for (int i = 0; i < 2; ++i) {
      const int mb = m0 + wm + i * 16 + quad * 4;
      float r[4];
#pragma unroll
      for (int reg = 0; reg < 4; ++reg) {
        float v = acc[i][j][reg] + bv;
        if (ACT) v = v > 0.f ? v : 0.01f * v;
        if (RES) v += Res[(long long)(mb + reg) * Nn + col];
        r[reg] = v;
      }
      if (OM == 0) {
#pragma unroll
        for (int reg = 0; reg < 4; ++reg)
          outF[(long long)(mb + reg) * Nn + col] = r[reg];
      } else if (OM == 1) {
#pragma unroll
        for (int reg = 0; reg < 4; ++reg)
          outB[(long long)(mb + reg) * Nn + col] = f2bf(r[reg]);
      } else if (OM == 2) {   // dual: fp32 + bf16 copies of [m][n]
#pragma unroll
        for (int reg = 0; reg < 4; ++reg) {
          outF[(long long)(mb + reg) * Nn + col] = r[reg];
          outB[(long long)(mb + reg) * Nn + col] = f2bf(r[reg]);
        }
      } else {  // OM == 4: fp32 [B][C][N], m flattened over (b,n)
        const float4 st = {r[0], r[1], r[2], r[3]};
        *(float4*)&outF[((long long)((mb >> 12) * Cv + col)) * Nv + (mb & 4095)] = st;
      }
    }
  }
}

// ---------------------------------------------------------------------------
// Cluster centers (accumulate only; attn normalizes on load)
// ---------------------------------------------------------------------------
__global__ __launch_bounds__(256) void center_accum(
    const unsigned short* __restrict__ kb, const int* __restrict__ labels,
    float* __restrict__ cent, float* __restrict__ cnts)
{
  __shared__ int lab_s[512];
  const int bx = blockIdx.x;           // Bv*Kv*8 blocks
  const int chunk = bx & 7;
  const int kk = (bx >> 3) & 15;
  const int b = bx >> 7;
  const int c = threadIdx.x;
  const int nbase = chunk * 512;
  for (int i = threadIdx.x; i < 512; i += 256) lab_s[i] = labels[b * Nv + nbase + i];
  __syncthreads();
  float acc = 0.f;
  int cnt = 0;
#pragma unroll 4
  for (int i = 0; i < 512; ++i) {
    if (lab_s[i] == kk) {              // wave-uniform branch on LDS value
      acc += bf2f(kb[(long long)(b * Nv + nbase + i) * Cv + c]);
      ++cnt;
    }
  }
  atomicAdd(&cent[(b * Kv + kk) * Cv + c], acc);
  if (c == 0) atomicAdd(&cnts[b * Kv + kk], (float)cnt);
}

// ---------------------------------------------------------------------------
// MFMA flash attention, split-m x2 (R12 body). LDS 32000B overlays; main-loop
// barriers are lgkmcnt-only (global loads never drained at barriers).
// p = exp2(s), no shift. cvt_pk P pack. Partials: opart/lpart as before.
// ---------------------------------------------------------------------------
__global__ __launch_bounds__(256) void attn_k(
    const unsigned short* __restrict__ qb, const unsigned short* __restrict__ kb,
    const unsigned short* __restrict__ vtb, const float* __restrict__ cent,
    const float* __restrict__ cnts, const int* __restrict__ labels,
    const float* __restrict__ pc, float* __restrict__ opart, float* __restrict__ lpart)
{
  __shared__ __align__(16) unsigned short q_s[64][72];   // q rows, then P tiles
  __shared__ __align__(16) unsigned short k_s[64][72];   // centers, then K tile
  __shared__ __align__(16) unsigned short vt_s[64][72];
  __shared__ float ac_s[64][17];

  const int tid = threadIdx.x;
  const int lane = tid & 63, w = tid >> 6;
  const int lr = lane & 15, quad = lane >> 4;
  const int bx = blockIdx.x;
  const int qt = bx & 63, h = (bx >> 6) & 3, b = (bx >> 8) & 1;
  const int part = bx >> 9;
  const int n0 = qt * 64;
  const int mbase = part * 2048;
  const int sr2 = tid >> 2, so2 = (tid & 3) * 16;
  const int row_l = w * 16 + quad * 4;
  const long long pcb = (long long)b * Nv * Nv;

  // ---- prologue: stage q + normalized centers (centers live in k_s)
  {
    const unsigned short* src = qb + ((long long)(b * Nv + n0 + sr2)) * Cv + h * HDv + so2;
    *(uint4*)&q_s[sr2][so2] = *(const uint4*)src;
    *(uint4*)&q_s[sr2][so2 + 8] = *(const uint4*)(src + 8);
  }
  float* c_s = (float*)&k_s[0][0];   // [16][68] floats = 4352 B
  for (int idx = tid; idx < Kv * HDv; idx += 256) {
    const int kk = idx >> 6, d = idx & 63;
    c_s[kk * 68 + d] = cent[((long long)(b * Kv + kk)) * Cv + h * HDv + d]
                       / (cnts[b * Kv + kk] + 1e-6f);
  }

  // issue tile-0 k/v + pc + labm loads while the block syncs
  uint4 ka0, ka1, va0, va1;
  float pc1[4][4];
  int labm1[4], labq[4];
  {
    const long long ks = ((long long)(b * Nv + mbase + sr2)) * Cv + h * HDv + so2;
    ka0 = *(const uint4*)(kb + ks); ka1 = *(const uint4*)(kb + ks + 8);
    const long long vs = ((long long)(b * Cv + h * HDv + sr2)) * Nv + mbase + so2;
    va0 = *(const uint4*)(vtb + vs); va1 = *(const uint4*)(vtb + vs + 8);
  }
#pragma unroll
  for (int sub = 0; sub < 4; ++sub) {
    labm1[sub] = labels[b * Nv + mbase + sub * 16 + lr];
#pragma unroll
    for (int reg = 0; reg < 4; ++reg)
      pc1[sub][reg] = pc[pcb + (long long)(n0 + row_l + reg) * Nv + mbase + sub * 16 + lr];
  }
#pragma unroll
  for (int reg = 0; reg < 4; ++reg) labq[reg] = labels[b * Nv + n0 + row_l + reg];

  __syncthreads();               // q_s, c_s visible
  // ac_s[r][k] = (q_r scaled) . center_k
  for (int idx = tid; idx < 64 * Kv; idx += 256) {
    const int r = idx >> 4, kk = idx & 15;
    float s = 0.f;
#pragma unroll
    for (int d = 0; d < HDv; ++d) s += bf2f(q_s[r][d]) * c_s[kk * 68 + d];
    ac_s[r][kk] = s;
  }
  const bf16x8 qa0 = *(const bf16x8*)&q_s[w * 16 + lr][quad * 8];
  const bf16x8 qa1 = *(const bf16x8*)&q_s[w * 16 + lr][32 + quad * 8];
  __syncthreads();               // ac_s visible; all q_s/c_s reads done

  // tile-0 acg gather (register-resident select operand)
  float acg[4][4];
#pragma unroll
  for (int sub = 0; sub < 4; ++sub)
#pragma unroll
    for (int reg = 0; reg < 4; ++reg)
      acg[sub][reg] = ac_s[row_l + reg][labm1[sub]];

  // stage tile 0 from regs (k_s stops being centers here)
  *(uint4*)&k_s[sr2][so2] = ka0; *(uint4*)&k_s[sr2][so2 + 8] = ka1;
  *(uint4*)&vt_s[sr2][so2] = va0; *(uint4*)&vt_s[sr2][so2 + 8] = va1;
  __syncthreads();               // tile 0 visible

  f32x4 oacc[4];
#pragma unroll
  for (int s2 = 0; s2 < 4; ++s2) oacc[s2] = (f32x4){0.f, 0.f, 0.f, 0.f};
  float lrow[4] = {0.f, 0.f, 0.f, 0.f};

  for (int t = 0; t < 32; ++t) {
    const int m0 = mbase + t * 64;
    const bool has = (t < 31);

    // prefetch next tile k/v into regs (stays in flight across barriers)
    if (has) {
      const long long ks = ((long long)(b * Nv + m0 + 64 + sr2)) * Cv + h * HDv + so2;
      ka0 = *(const uint4*)(kb + ks); ka1 = *(const uint4*)(kb + ks + 8);
      const long long vs = ((long long)(b * Cv + h * HDv + sr2)) * Nv + m0 + 64 + so2;
      va0 = *(const uint4*)(vtb + vs); va1 = *(const uint4*)(vtb + vs + 8);
    }

    // QK^T
    f32x4 sacc[4];
    __builtin_amdgcn_s_setprio(1);
#pragma unroll
    for (int sub = 0; sub < 4; ++sub) {
      const bf16x8 kb0 = *(const bf16x8*)&k_s[sub * 16 + lr][quad * 8];
      const bf16x8 kb1 = *(const bf16x8*)&k_s[sub * 16 + lr][32 + quad * 8];
      f32x4 s = (f32x4){0.f, 0.f, 0.f, 0.f};
      s = __builtin_amdgcn_mfma_f32_16x16x32_bf16(qa0, kb0, s, 0, 0, 0);
      s = __builtin_amdgcn_mfma_f32_16x16x32_bf16(qa1, kb1, s, 0, 0, 0);
      sacc[sub] = s;
    }
    __builtin_amdgcn_s_setprio(0);

    // adaptive select + exp2(s), cvt_pk P pack into q_s rows (per-wave)
#pragma unroll
    for (int sub = 0; sub < 4; ++sub) {
      float p4[4];
#pragma unroll
      for (int reg = 0; reg < 4; ++reg) {
        const float s = (labm1[sub] == labq[reg]) ? sacc[sub][reg]
                                                  : acg[sub][reg] * pc1[sub][reg];
        const float p = exp2_raw(s);
        lrow[reg] += p;
        p4[reg] = p;
      }
      const unsigned int pk01 = cvt_pk_bf16(p4[0], p4[1]);
      const unsigned int pk23 = cvt_pk_bf16(p4[2], p4[3]);
      unsigned short* pp = &q_s[w * 16 + quad * 4][sub * 16 + lr];
      pp[0]   = (unsigned short)pk01;
      pp[72]  = (unsigned short)(pk01 >> 16);
      pp[144] = (unsigned short)pk23;
      pp[216] = (unsigned short)(pk23 >> 16);
    }

    // pc/labm consumed -> issue next tile's loads (in flight across barriers,
    // consumed at next tile's select: full-tile latency window)
    if (has) {
#pragma unroll
      for (int sub = 0; sub < 4; ++sub) {
        labm1[sub] = labels[b * Nv + m0 + 64 + sub * 16 + lr];
#pragma unroll
        for (int reg = 0; reg < 4; ++reg)
          pc1[sub][reg] = pc[pcb + (long long)(n0 + row_l + reg) * Nv + m0 + 64 + sub * 16 + lr];
      }
    }

    // PV (same-wave LDS in-order; P lives in this wave's q_s rows)
    const bf16x8 pa0 = *(const bf16x8*)&q_s[w * 16 + lr][quad * 8];
    const bf16x8 pa1 = *(const bf16x8*)&q_s[w * 16 + lr][32 + quad * 8];
    __builtin_amdgcn_s_setprio(1);
#pragma unroll
    for (int sub = 0; sub < 4; ++sub) {
      const bf16x8 vb0 = *(const bf16x8*)&vt_s[sub * 16 + lr][quad * 8];
      const bf16x8 vb1 = *(const bf16x8*)&vt_s[sub * 16 + lr][32 + quad * 8];
      oacc[sub] = __builtin_amdgcn_mfma_f32_16x16x32_bf16(pa0, vb0, oacc[sub], 0, 0, 0);
      oacc[sub] = __builtin_amdgcn_mfma_f32_16x16x32_bf16(pa1, vb1, oacc[sub], 0, 0, 0);
    }
    __builtin_amdgcn_s_setprio(0);

    // gather next tile's acg (LDS latency hides under barrier + next QK)
    if (has) {
#pragma unroll
      for (int sub = 0; sub < 4; ++sub)
#pragma unroll
        for (int reg = 0; reg < 4; ++reg)
          acg[sub][reg] = ac_s[row_l + reg][labm1[sub]];
    }

    barrier_lds();               // all waves done reading k_s/vt_s (LDS only)
    if (has) {
      *(uint4*)&k_s[sr2][so2] = ka0; *(uint4*)&k_s[sr2][so2 + 8] = ka1;
      *(uint4*)&vt_s[sr2][so2] = va0; *(uint4*)&vt_s[sr2][so2 + 8] = va1;
    }
    barrier_lds();               // next tile visible (LDS only)
  }

  // epilogue: partial sums (no normalization; combine_k divides)
#pragma unroll
  for (int reg = 0; reg < 4; ++reg) {
    float l = lrow[reg];
    l += __shfl_xor(l, 1); l += __shfl_xor(l, 2);
    l += __shfl_xor(l, 4); l += __shfl_xor(l, 8);
    const int row = n0 + row_l + reg;
    const long long obase = (long long)part * 2097152 + ((long long)(b * Nv + row)) * Cv + h * HDv;
#pragma unroll
    for (int sub = 0; sub < 4; ++sub)
      opart[obase + sub * 16 + lr] = oacc[sub][reg];
    if (lr == 0)
      lpart[part * 32768 + (b * 4 + h) * 4096 + row] = l;
  }
}

// ---------------------------------------------------------------------------
// Combine split-m partials: aob = (o0+o1)/(l0+l1), bf16
// ---------------------------------------------------------------------------
__global__ __launch_bounds__(256) void combine_k(
    const float* __restrict__ op, const float* __restrict__ lp,
    unsigned short* __restrict__ aob)
{
  const long long i4 = ((long long)blockIdx.x * 256 + threadIdx.x) * 4;
  const int c = (int)(i4 & 255), n = (int)((i4 >> 8) & 4095), b = (int)(i4 >> 20);
  const int h = c >> 6;
  const float l = lp[(b * 4 + h) * 4096 + n] + lp[32768 + (b * 4 + h) * 4096 + n];
  const float inv = 1.f / l;
  const float4 a = *(const float4*)&op[i4];
  const float4 d = *(const float4*)&op[2097152 + i4];
  uint2 pk;
  pk.x = cvt_pk_bf16((a.x + d.x) * inv, (a.y + d.y) * inv);
  pk.y = cvt_pk_bf16((a.z + d.z) * inv, (a.w + d.w) * inv);
  *(uint2*)&aob[i4] = pk;
}

// ---------------------------------------------------------------------------
extern "C" void kernel_launch(void* const* d_in, const int* in_sizes, int n_in,
                              void* d_out, int out_size, void* d_ws, size_t ws_size,
                              hipStream_t stream)
{
  const float* q_img = (const float*)d_in[0];
  const float* k_img = (const float*)d_in[1];
  const float* v_img = (const float*)d_in[2];
  const int* labels  = (const int*)d_in[3];
  const float* pc    = (const float*)d_in[4];
  const float* Wq  = (const float*)d_in[5];  const float* bq  = (const float*)d_in[6];
  const float* Wk  = (const float*)d_in[7];  const float* bk  = (const float*)d_in[8];
  const float* Wv  = (const float*)d_in[9];  const float* bv  = (const float*)d_in[10];
  const float* W11 = (const float*)d_in[11]; const float* b11 = (const float*)d_in[12];
  const float* W12 = (const float*)d_in[13]; const float* b12 = (const float*)d_in[14];
  const float* W21 = (const float*)d_in[15]; const float* b21 = (const float*)d_in[16];
  const float* W22 = (const float*)d_in[17]; const float* b22 = (const float*)d_in[18];
  float* outp = (float*)d_out;

  const long long SZ = (long long)Bv * Nv * Cv;     // 2,097,152
  // fp32 region (~32.3 MB)
  float* ws    = (float*)d_ws;
  float* vpp   = ws;                       // v proj fp32
  float* rs1   = vpp + SZ;                 // MLP1 out fp32
  float* opart = rs1 + SZ;                 // attn partials [2][B][N][C]
  float* lpart = opart + 2 * SZ;           // [2][B][NH][N]
  float* cent  = lpart + 65536;            // [B][K][C]
  float* cnts  = cent + Bv * Kv * Cv;      // [B][K]
  // bf16 region (~25.4 MB)
  unsigned short* wt   = (unsigned short*)(cnts + Bv * Kv);
  unsigned short* qbf  = wt + 720896;      // [B][N][C] pre-scaled 0.125*log2e
  unsigned short* kbf  = qbf + SZ;
  unsigned short* vtb  = kbf + SZ;         // [B][C][N]
  unsigned short* aob  = vtb + SZ;         // attn out bf16; later rs1-bf16
  unsigned short* h1b  = aob + SZ;         // MLP hidden [2N][2C]
  unsigned short* imgT = aob;              // overlay (dead after proj)

  // prep (wt_k z==7 zeros cent+cnts)
  imgt_k<<<dim3(Nv / 32, Cv / 32, 6), dim3(32, 8), 0, stream>>>(q_img, k_img, v_img, imgT);
  WP wp = {{Wq, Wk, Wv, W11, W12, W21, W22}};
  wt_k<<<dim3(16, 16, 8), dim3(32, 8), 0, stream>>>(wp, wt, cent, Bv * Kv * Cv + Bv * Kv);

  // fused q/k/v projections (64x64 tiles, 1536 blocks = 6/CU)
  proj64_k<<<dim3(64, 4, 6), 256, 0, stream>>>(imgT, wt, bq, bk, bv, qbf, kbf, vpp, vtb);

  // cluster centers (normalization folded into attn)
  center_accum<<<dim3(Bv * Kv * 8), 256, 0, stream>>>(kbf, labels, cent, cnts);

  // attention (split-m x2) + combine
  attn_k<<<dim3(1024), 256, 0, stream>>>(qbf, kbf, vtb, cent, cnts, labels, pc, opart, lpart);
  combine_k<<<dim3(2048), 256, 0, stream>>>(opart, lpart, aob);

  // MLP1: h1 = leaky(aob@W11+b11); rs1 = vpp + h1@W12+b12 (fp32 + bf16->aob)
  mm64_k<true, 1, 0, 1><<<dim3(128, 8), 256, 0, stream>>>(
      aob, wt + 196608, b11, nullptr, nullptr, h1b, 2 * Nv, 2 * Cv, Cv);
  mm64_k<true, 0, 1, 2><<<dim3(128, 4), 256, 0, stream>>>(
      h1b, wt + 327680, b12, vpp, rs1, aob, 2 * Nv, Cv, 2 * Cv);

  // MLP2: h2 = leaky(rs1b@W21+b21); out = rs1 + h2@W22+b22 -> [B][C][H][W]
  mm64_k<true, 1, 0, 1><<<dim3(128, 8), 256, 0, stream>>>(
      aob, wt + 458752, b21, nullptr, nullptr, h1b, 2 * Nv, 2 * Cv, Cv);
  mm64_k<true, 0, 1, 4><<<dim3(128, 4), 256, 0, stream>>>(
      h1b, wt + 589824, b22, rs1, outp, nullptr, 2 * Nv, Cv, 2 * Cv);
}